// Round 1
// baseline (527.515 us; speedup 1.0000x reference)
//
#include <hip/hip_runtime.h>
#include <hip/hip_bf16.h>

typedef __bf16 bf16x8 __attribute__((ext_vector_type(8)));
typedef float f32x4 __attribute__((ext_vector_type(4)));
typedef unsigned short ushort_t;

constexpr int NB = 32768;   // batch rows
constexpr int D1 = 1024;    // K
constexpr int D2 = 4096;    // N
constexpr float BETA_LOG2E = 14.4269504088896340736f; // 10 * log2(e)

__device__ __forceinline__ ushort_t f32_to_bf16(float f) {
  union { float f; unsigned int u; } x; x.f = f;
  unsigned int r = x.u + 0x7FFFu + ((x.u >> 16) & 1u);  // RNE
  return (ushort_t)(r >> 16);
}

__device__ __forceinline__ void async_copy16(const void* g, void* l) {
  __builtin_amdgcn_global_load_lds(
      (const __attribute__((address_space(1))) void*)g,
      (__attribute__((address_space(3))) void*)l, 16, 0, 0);
}

// ---- 1. partial column sum-of-squares of W: sq[j] += sum_k W[k][j]^2 ----
__global__ void colnorm_partial(const float* __restrict__ W, float* __restrict__ sq) {
  int j = blockIdx.x * 256 + threadIdx.x;   // gridDim.x = 16
  int k0 = blockIdx.y * 64;                 // gridDim.y = 16
  float acc = 0.f;
#pragma unroll 8
  for (int k = 0; k < 64; ++k) {
    float w = W[(size_t)(k0 + k) * D2 + j];
    acc += w * w;
  }
  atomicAdd(&sq[j], acc);
}

// ---- 2. g1 fp32 -> bf16, row-major [NB][D1] ----
__global__ void convert_a(const float* __restrict__ g1, ushort_t* __restrict__ g1b) {
  size_t i = ((size_t)blockIdx.x * 256 + threadIdx.x) * 8;
  float4 v0 = *(const float4*)(g1 + i);
  float4 v1 = *(const float4*)(g1 + i + 4);
  uint4 o;
  o.x = f32_to_bf16(v0.x) | ((unsigned)f32_to_bf16(v0.y) << 16);
  o.y = f32_to_bf16(v0.z) | ((unsigned)f32_to_bf16(v0.w) << 16);
  o.z = f32_to_bf16(v1.x) | ((unsigned)f32_to_bf16(v1.y) << 16);
  o.w = f32_to_bf16(v1.z) | ((unsigned)f32_to_bf16(v1.w) << 16);
  *(uint4*)(g1b + i) = o;
}

// ---- 3. normalize + transpose: nWt[j][k] = bf16(W[k][j] / sqrt(sq[j])) ----
__global__ void convert_b(const float* __restrict__ W, const float* __restrict__ sq,
                          ushort_t* __restrict__ nWt) {
  __shared__ float tile[64][65];
  int t = threadIdx.x;                 // 256
  int j0 = blockIdx.x * 64;            // gridDim.x = 64
  int k0 = blockIdx.y * 64;            // gridDim.y = 16
  int c = t & 63, r4 = t >> 6;
#pragma unroll
  for (int s = 0; s < 16; ++s) {
    int k = s * 4 + r4;
    tile[k][c] = W[(size_t)(k0 + k) * D2 + j0 + c];
  }
  __syncthreads();
#pragma unroll
  for (int s = 0; s < 16; ++s) {
    int jj = s * 4 + r4;
    float inv = 1.0f / sqrtf(sq[j0 + jj]);
    nWt[(size_t)(j0 + jj) * D1 + k0 + c] = f32_to_bf16(tile[c][jj] * inv);
  }
}

// ---- 4. fused GEMM + exp-sum. A[NB][D1] bf16, Bt[D2][D1] bf16 (both K-major).
// 128x128 tile, BK=64, 256 thr = 4 waves in 2x2, each wave 4x4 of 16x16x32 MFMA.
__global__ __launch_bounds__(256, 2)
void gemm_expsum(const ushort_t* __restrict__ A, const ushort_t* __restrict__ Bt,
                 float* __restrict__ s) {
  __shared__ __align__(16) ushort_t As[128 * 64];
  __shared__ __align__(16) ushort_t Bs[128 * 64];

  const int t = threadIdx.x;
  const int row0 = blockIdx.x * 128;   // gridDim.x = 256
  const int col0 = blockIdx.y * 128;   // gridDim.y = 32
  const int lane = t & 63;
  const int wave = t >> 6;
  const int wm = (wave >> 1) * 64;     // wave row offset in tile
  const int wn = (wave & 1) * 64;      // wave col offset in tile
  const int llo = lane & 15, lhi = lane >> 4;

  f32x4 acc[4][4] = {};

  // staging addresses: sweep i covers rows [i*32, i*32+32); thread t -> row t/8, k (t%8)*8
  const ushort_t* gA = A  + (size_t)(row0 + (t >> 3)) * D1 + (t & 7) * 8;
  const ushort_t* gB = Bt + (size_t)(col0 + (t >> 3)) * D1 + (t & 7) * 8;
  ushort_t* lA = As + t * 8;   // byte offset t*16 (lane-order contiguous)
  ushort_t* lB = Bs + t * 8;

  for (int kt = 0; kt < D1; kt += 64) {
#pragma unroll
    for (int i = 0; i < 4; ++i) {
      async_copy16(gA + (size_t)i * 32 * D1 + kt, lA + i * 2048);
      async_copy16(gB + (size_t)i * 32 * D1 + kt, lB + i * 2048);
    }
    __syncthreads();   // drains vmcnt(0): staged LDS data visible
#pragma unroll
    for (int kk = 0; kk < 64; kk += 32) {
      bf16x8 af[4], bq[4];
#pragma unroll
      for (int mi = 0; mi < 4; ++mi)
        af[mi] = *(const bf16x8*)(As + (wm + mi * 16 + llo) * 64 + kk + lhi * 8);
#pragma unroll
      for (int ni = 0; ni < 4; ++ni)
        bq[ni] = *(const bf16x8*)(Bs + (wn + ni * 16 + llo) * 64 + kk + lhi * 8);
#pragma unroll
      for (int mi = 0; mi < 4; ++mi)
#pragma unroll
        for (int ni = 0; ni < 4; ++ni)
          acc[mi][ni] = __builtin_amdgcn_mfma_f32_16x16x32_bf16(af[mi], bq[ni], acc[mi][ni], 0, 0, 0);
    }
    __syncthreads();   // all waves done with LDS before next stage overwrites
  }

  // epilogue: per-row sum of exp(beta * x2). C/D layout: col=lane&15, row=(lane>>4)*4+reg.
#pragma unroll
  for (int mi = 0; mi < 4; ++mi) {
    float rs[4];
#pragma unroll
    for (int r = 0; r < 4; ++r) {
      float v = 0.f;
#pragma unroll
      for (int ni = 0; ni < 4; ++ni)
        v += exp2f(acc[mi][ni][r] * BETA_LOG2E);
      rs[r] = v;
    }
    // sum across the 16 columns held by lanes differing in low 4 bits
#pragma unroll
    for (int m = 1; m < 16; m <<= 1) {
#pragma unroll
      for (int r = 0; r < 4; ++r)
        rs[r] += __shfl_xor(rs[r], m, 64);
    }
    if (llo == 0) {
      int row = row0 + wm + mi * 16 + lhi * 4;
#pragma unroll
      for (int r = 0; r < 4; ++r)
        atomicAdd(&s[row + r], rs[r]);
    }
  }
}

// ---- 5. out[b] = -(1/beta) * log(s[b]) ----
__global__ void finish_kernel(const float* __restrict__ s, float* __restrict__ out) {
  int b = blockIdx.x * 256 + threadIdx.x;
  out[b] = -0.1f * logf(s[b]);
}

extern "C" void kernel_launch(void* const* d_in, const int* in_sizes, int n_in,
                              void* d_out, int out_size, void* d_ws, size_t ws_size,
                              hipStream_t stream) {
  const float* g1 = (const float*)d_in[0];
  const float* W  = (const float*)d_in[1];
  float* out = (float*)d_out;

  char* ws = (char*)d_ws;
  float* s       = (float*)ws;                          // 32768 * 4 = 128 KiB
  float* sq      = (float*)(ws + 131072);               // 4096 * 4  = 16 KiB
  ushort_t* nWt  = (ushort_t*)(ws + 147456);            // 4096*1024*2 = 8 MiB
  ushort_t* g1b  = (ushort_t*)(ws + 147456 + 8388608);  // 32768*1024*2 = 64 MiB

  hipMemsetAsync(ws, 0, 147456, stream);  // zero s + sq

  colnorm_partial<<<dim3(16, 16), 256, 0, stream>>>(W, sq);
  convert_b<<<dim3(64, 16), 256, 0, stream>>>(W, sq, nWt);
  convert_a<<<dim3(16384), 256, 0, stream>>>(g1, g1b);
  gemm_expsum<<<dim3(256, 32), 256, 0, stream>>>(g1b, nWt, s);
  finish_kernel<<<dim3(128), 256, 0, stream>>>(s, out);
}

// Round 2
// 506.165 us; speedup vs baseline: 1.0422x; 1.0422x over previous
//
#include <hip/hip_runtime.h>
#include <hip/hip_bf16.h>

typedef __bf16 bf16x8 __attribute__((ext_vector_type(8)));
typedef float f32x4 __attribute__((ext_vector_type(4)));
typedef unsigned short ushort_t;

constexpr int NB = 32768;   // batch rows
constexpr int D1 = 1024;    // K
constexpr int D2 = 4096;    // N
constexpr float BETA_LOG2E = 14.4269504088896340736f; // 10 * log2(e)

__device__ __forceinline__ ushort_t f32_to_bf16(float f) {
  union { float f; unsigned int u; } x; x.f = f;
  unsigned int r = x.u + 0x7FFFu + ((x.u >> 16) & 1u);  // RNE
  return (ushort_t)(r >> 16);
}

__device__ __forceinline__ void async_copy16(const void* g, void* l) {
  __builtin_amdgcn_global_load_lds(
      (const __attribute__((address_space(1))) void*)g,
      (__attribute__((address_space(3))) void*)l, 16, 0, 0);
}

// ---- 1. partial column sum-of-squares of W: sq[j] += sum_k W[k][j]^2 ----
__global__ void colnorm_partial(const float* __restrict__ W, float* __restrict__ sq) {
  int j = blockIdx.x * 256 + threadIdx.x;   // gridDim.x = 16
  int k0 = blockIdx.y * 64;                 // gridDim.y = 16
  float acc = 0.f;
#pragma unroll 8
  for (int k = 0; k < 64; ++k) {
    float w = W[(size_t)(k0 + k) * D2 + j];
    acc += w * w;
  }
  atomicAdd(&sq[j], acc);
}

// ---- 2. g1 fp32 -> bf16, row-major [NB][D1] ----
__global__ void convert_a(const float* __restrict__ g1, ushort_t* __restrict__ g1b) {
  size_t i = ((size_t)blockIdx.x * 256 + threadIdx.x) * 8;
  float4 v0 = *(const float4*)(g1 + i);
  float4 v1 = *(const float4*)(g1 + i + 4);
  uint4 o;
  o.x = f32_to_bf16(v0.x) | ((unsigned)f32_to_bf16(v0.y) << 16);
  o.y = f32_to_bf16(v0.z) | ((unsigned)f32_to_bf16(v0.w) << 16);
  o.z = f32_to_bf16(v1.x) | ((unsigned)f32_to_bf16(v1.y) << 16);
  o.w = f32_to_bf16(v1.z) | ((unsigned)f32_to_bf16(v1.w) << 16);
  *(uint4*)(g1b + i) = o;
}

// ---- 3. normalize + transpose: nWt[j][k] = bf16(W[k][j] / sqrt(sq[j])) ----
__global__ void convert_b(const float* __restrict__ W, const float* __restrict__ sq,
                          ushort_t* __restrict__ nWt) {
  __shared__ float tile[64][65];
  int t = threadIdx.x;                 // 256
  int j0 = blockIdx.x * 64;            // gridDim.x = 64
  int k0 = blockIdx.y * 64;            // gridDim.y = 16
  int c = t & 63, r4 = t >> 6;
#pragma unroll
  for (int s = 0; s < 16; ++s) {
    int k = s * 4 + r4;
    tile[k][c] = W[(size_t)(k0 + k) * D2 + j0 + c];
  }
  __syncthreads();
#pragma unroll
  for (int s = 0; s < 16; ++s) {
    int jj = s * 4 + r4;
    float inv = 1.0f / sqrtf(sq[j0 + jj]);
    nWt[(size_t)(j0 + jj) * D1 + k0 + c] = f32_to_bf16(tile[c][jj] * inv);
  }
}

// ---- 4. fused GEMM + exp-sum. A[NB][D1] bf16, Bt[D2][D1] bf16 (both K-major).
// 128x128 tile, BK=64, 256 thr = 4 waves in 2x2, each wave 4x4 of 16x16x32 MFMA.
// LDS layout XOR-swizzled: 16B segment slot (row, s) holds global segment
// (row, s ^ (row&7)) -> fragment ds_read_b128 spreads over all 32 banks.
__global__ __launch_bounds__(256, 3)
void gemm_expsum(const ushort_t* __restrict__ A, const ushort_t* __restrict__ Bt,
                 float* __restrict__ s) {
  __shared__ __align__(16) ushort_t As[128 * 64];
  __shared__ __align__(16) ushort_t Bs[128 * 64];

  const int t = threadIdx.x;
  const int row0 = blockIdx.x * 128;   // gridDim.x = 256
  const int col0 = blockIdx.y * 128;   // gridDim.y = 32
  const int lane = t & 63;
  const int wave = t >> 6;
  const int wm = (wave >> 1) * 64;     // wave row offset in tile
  const int wn = (wave & 1) * 64;      // wave col offset in tile
  const int llo = lane & 15, lhi = lane >> 4;

  f32x4 acc[4][4] = {};

  // staging: thread t owns LDS slot (row=t>>3, seg=t&7); fetches global
  // segment (t&7) ^ ((t>>3)&7). Sweep i advances row by 32 (multiple of 8,
  // so row&7 — and hence the swizzle — is i-invariant).
  const int srow = t >> 3;
  const int sseg = (t & 7) ^ (srow & 7);
  const ushort_t* gA = A  + (size_t)(row0 + srow) * D1 + sseg * 8;
  const ushort_t* gB = Bt + (size_t)(col0 + srow) * D1 + sseg * 8;
  ushort_t* lA = As + t * 8;   // byte offset t*16 (lane-order contiguous)
  ushort_t* lB = Bs + t * 8;

  for (int kt = 0; kt < D1; kt += 64) {
#pragma unroll
    for (int i = 0; i < 4; ++i) {
      async_copy16(gA + (size_t)i * 32 * D1 + kt, lA + i * 2048);
      async_copy16(gB + (size_t)i * 32 * D1 + kt, lB + i * 2048);
    }
    __syncthreads();   // drains vmcnt(0): staged LDS data visible
#pragma unroll
    for (int kk = 0; kk < 64; kk += 32) {
      // fragment row r has r&7 == llo&7 for every mi/ni -> shared swizzle
      const int sw = (((kk >> 3) + lhi) ^ (llo & 7)) * 8;
      bf16x8 af[4], bq[4];
#pragma unroll
      for (int mi = 0; mi < 4; ++mi)
        af[mi] = *(const bf16x8*)(As + (wm + mi * 16 + llo) * 64 + sw);
#pragma unroll
      for (int ni = 0; ni < 4; ++ni)
        bq[ni] = *(const bf16x8*)(Bs + (wn + ni * 16 + llo) * 64 + sw);
#pragma unroll
      for (int mi = 0; mi < 4; ++mi)
#pragma unroll
        for (int ni = 0; ni < 4; ++ni)
          acc[mi][ni] = __builtin_amdgcn_mfma_f32_16x16x32_bf16(af[mi], bq[ni], acc[mi][ni], 0, 0, 0);
    }
    __syncthreads();   // all waves done with LDS before next stage overwrites
  }

  // epilogue: per-row sum of exp(beta * x2). C/D layout: col=lane&15, row=(lane>>4)*4+reg.
#pragma unroll
  for (int mi = 0; mi < 4; ++mi) {
    float rs[4];
#pragma unroll
    for (int r = 0; r < 4; ++r) {
      float v = 0.f;
#pragma unroll
      for (int ni = 0; ni < 4; ++ni)
        v += exp2f(acc[mi][ni][r] * BETA_LOG2E);
      rs[r] = v;
    }
    // sum across the 16 columns held by lanes differing in low 4 bits
#pragma unroll
    for (int m = 1; m < 16; m <<= 1) {
#pragma unroll
      for (int r = 0; r < 4; ++r)
        rs[r] += __shfl_xor(rs[r], m, 64);
    }
    if (llo == 0) {
      int row = row0 + wm + mi * 16 + lhi * 4;
#pragma unroll
      for (int r = 0; r < 4; ++r)
        atomicAdd(&s[row + r], rs[r]);
    }
  }
}

// ---- 5. out[b] = -(1/beta) * log(s[b]) ----
__global__ void finish_kernel(const float* __restrict__ s, float* __restrict__ out) {
  int b = blockIdx.x * 256 + threadIdx.x;
  out[b] = -0.1f * logf(s[b]);
}

extern "C" void kernel_launch(void* const* d_in, const int* in_sizes, int n_in,
                              void* d_out, int out_size, void* d_ws, size_t ws_size,
                              hipStream_t stream) {
  const float* g1 = (const float*)d_in[0];
  const float* W  = (const float*)d_in[1];
  float* out = (float*)d_out;

  char* ws = (char*)d_ws;
  float* s       = (float*)ws;                          // 32768 * 4 = 128 KiB
  float* sq      = (float*)(ws + 131072);               // 4096 * 4  = 16 KiB
  ushort_t* nWt  = (ushort_t*)(ws + 147456);            // 4096*1024*2 = 8 MiB
  ushort_t* g1b  = (ushort_t*)(ws + 147456 + 8388608);  // 32768*1024*2 = 64 MiB

  hipMemsetAsync(ws, 0, 147456, stream);  // zero s + sq

  colnorm_partial<<<dim3(16, 16), 256, 0, stream>>>(W, sq);
  convert_b<<<dim3(64, 16), 256, 0, stream>>>(W, sq, nWt);
  convert_a<<<dim3(16384), 256, 0, stream>>>(g1, g1b);
  gemm_expsum<<<dim3(256, 32), 256, 0, stream>>>(g1b, nWt, s);
  finish_kernel<<<dim3(128), 256, 0, stream>>>(s, out);
}

// Round 3
// 480.762 us; speedup vs baseline: 1.0972x; 1.0528x over previous
//
#include <hip/hip_runtime.h>
#include <hip/hip_bf16.h>

typedef __bf16 bf16x8 __attribute__((ext_vector_type(8)));
typedef float f32x4 __attribute__((ext_vector_type(4)));
typedef unsigned short ushort_t;

constexpr int NB = 32768;   // batch rows
constexpr int D1 = 1024;    // K
constexpr int D2 = 4096;    // N
constexpr float BETA_LOG2E = 14.4269504088896340736f; // 10 * log2(e)

__device__ __forceinline__ ushort_t f32_to_bf16(float f) {
  union { float f; unsigned int u; } x; x.f = f;
  unsigned int r = x.u + 0x7FFFu + ((x.u >> 16) & 1u);  // RNE
  return (ushort_t)(r >> 16);
}

__device__ __forceinline__ void async_copy16(const void* g, void* l) {
  __builtin_amdgcn_global_load_lds(
      (const __attribute__((address_space(1))) void*)g,
      (__attribute__((address_space(3))) void*)l, 16, 0, 0);
}

// ---- 1. partial column sum-of-squares of W: sq[j] += sum_k W[k][j]^2 ----
__global__ void colnorm_partial(const float* __restrict__ W, float* __restrict__ sq) {
  int j = blockIdx.x * 256 + threadIdx.x;   // gridDim.x = 16
  int k0 = blockIdx.y * 64;                 // gridDim.y = 16
  float acc = 0.f;
#pragma unroll 8
  for (int k = 0; k < 64; ++k) {
    float w = W[(size_t)(k0 + k) * D2 + j];
    acc += w * w;
  }
  atomicAdd(&sq[j], acc);
}

// ---- 2. g1 fp32 -> bf16, row-major [NB][D1] ----
__global__ void convert_a(const float* __restrict__ g1, ushort_t* __restrict__ g1b) {
  size_t i = ((size_t)blockIdx.x * 256 + threadIdx.x) * 8;
  float4 v0 = *(const float4*)(g1 + i);
  float4 v1 = *(const float4*)(g1 + i + 4);
  uint4 o;
  o.x = f32_to_bf16(v0.x) | ((unsigned)f32_to_bf16(v0.y) << 16);
  o.y = f32_to_bf16(v0.z) | ((unsigned)f32_to_bf16(v0.w) << 16);
  o.z = f32_to_bf16(v1.x) | ((unsigned)f32_to_bf16(v1.y) << 16);
  o.w = f32_to_bf16(v1.z) | ((unsigned)f32_to_bf16(v1.w) << 16);
  *(uint4*)(g1b + i) = o;
}

// ---- 3. normalize + transpose: nWt[j][k] = bf16(W[k][j] / sqrt(sq[j])) ----
__global__ void convert_b(const float* __restrict__ W, const float* __restrict__ sq,
                          ushort_t* __restrict__ nWt) {
  __shared__ float tile[64][65];
  int t = threadIdx.x;                 // 256
  int j0 = blockIdx.x * 64;            // gridDim.x = 64
  int k0 = blockIdx.y * 64;            // gridDim.y = 16
  int c = t & 63, r4 = t >> 6;
#pragma unroll
  for (int s = 0; s < 16; ++s) {
    int k = s * 4 + r4;
    tile[k][c] = W[(size_t)(k0 + k) * D2 + j0 + c];
  }
  __syncthreads();
#pragma unroll
  for (int s = 0; s < 16; ++s) {
    int jj = s * 4 + r4;
    float inv = 1.0f / sqrtf(sq[j0 + jj]);
    nWt[(size_t)(j0 + jj) * D1 + k0 + c] = f32_to_bf16(tile[c][jj] * inv);
  }
}

// ---- 4. fused GEMM + exp-sum. A[NB][D1] bf16, Bt[D2][D1] bf16 (both K-major).
// 128x128 tile, BK=64, 256 thr = 4 waves in 2x2, each wave 4x4 of 16x16x32 MFMA.
// Grid: x = col-blocks (32, fast axis), y = row-blocks (256) so co-resident
// blocks share one small A panel and the full (L2-resident) W -> near-
// compulsory HBM traffic. LDS XOR-swizzled (seg ^= row&7) -> 0 bank conflicts.
__global__ __launch_bounds__(256, 4)
void gemm_expsum(const ushort_t* __restrict__ A, const ushort_t* __restrict__ Bt,
                 float* __restrict__ s) {
  __shared__ __align__(16) ushort_t As[128 * 64];
  __shared__ __align__(16) ushort_t Bs[128 * 64];

  const int t = threadIdx.x;
  const int row0 = blockIdx.y * 128;   // gridDim.y = 256
  const int col0 = blockIdx.x * 128;   // gridDim.x = 32
  const int lane = t & 63;
  const int wave = t >> 6;
  const int wm = (wave >> 1) * 64;     // wave row offset in tile
  const int wn = (wave & 1) * 64;      // wave col offset in tile
  const int llo = lane & 15, lhi = lane >> 4;

  f32x4 acc[4][4] = {};

  // staging: thread t owns LDS slot (row=t>>3, seg=t&7); fetches global
  // segment (t&7) ^ ((t>>3)&7). Sweep i advances row by 32 (multiple of 8,
  // so row&7 — and hence the swizzle — is i-invariant).
  const int srow = t >> 3;
  const int sseg = (t & 7) ^ (srow & 7);
  const ushort_t* gA = A  + (size_t)(row0 + srow) * D1 + sseg * 8;
  const ushort_t* gB = Bt + (size_t)(col0 + srow) * D1 + sseg * 8;
  ushort_t* lA = As + t * 8;   // byte offset t*16 (lane-order contiguous)
  ushort_t* lB = Bs + t * 8;

  for (int kt = 0; kt < D1; kt += 64) {
#pragma unroll
    for (int i = 0; i < 4; ++i) {
      async_copy16(gA + (size_t)i * 32 * D1 + kt, lA + i * 2048);
      async_copy16(gB + (size_t)i * 32 * D1 + kt, lB + i * 2048);
    }
    __syncthreads();   // drains vmcnt(0): staged LDS data visible
#pragma unroll
    for (int kk = 0; kk < 64; kk += 32) {
      // fragment row r has r&7 == llo&7 for every mi/ni -> shared swizzle
      const int sw = (((kk >> 3) + lhi) ^ (llo & 7)) * 8;
      bf16x8 af[4], bq[4];
#pragma unroll
      for (int mi = 0; mi < 4; ++mi)
        af[mi] = *(const bf16x8*)(As + (wm + mi * 16 + llo) * 64 + sw);
#pragma unroll
      for (int ni = 0; ni < 4; ++ni)
        bq[ni] = *(const bf16x8*)(Bs + (wn + ni * 16 + llo) * 64 + sw);
#pragma unroll
      for (int mi = 0; mi < 4; ++mi)
#pragma unroll
        for (int ni = 0; ni < 4; ++ni)
          acc[mi][ni] = __builtin_amdgcn_mfma_f32_16x16x32_bf16(af[mi], bq[ni], acc[mi][ni], 0, 0, 0);
    }
    __syncthreads();   // all waves done with LDS before next stage overwrites
  }

  // epilogue: per-row sum of exp(beta * x2). C/D layout: col=lane&15, row=(lane>>4)*4+reg.
#pragma unroll
  for (int mi = 0; mi < 4; ++mi) {
    float rs[4];
#pragma unroll
    for (int r = 0; r < 4; ++r) {
      float v = 0.f;
#pragma unroll
      for (int ni = 0; ni < 4; ++ni)
        v += exp2f(acc[mi][ni][r] * BETA_LOG2E);
      rs[r] = v;
    }
    // sum across the 16 columns held by lanes differing in low 4 bits
#pragma unroll
    for (int m = 1; m < 16; m <<= 1) {
#pragma unroll
      for (int r = 0; r < 4; ++r)
        rs[r] += __shfl_xor(rs[r], m, 64);
    }
    if (llo == 0) {
      int row = row0 + wm + mi * 16 + lhi * 4;
#pragma unroll
      for (int r = 0; r < 4; ++r)
        atomicAdd(&s[row + r], rs[r]);
    }
  }
}

// ---- 5. out[b] = -(1/beta) * log(s[b]) ----
__global__ void finish_kernel(const float* __restrict__ s, float* __restrict__ out) {
  int b = blockIdx.x * 256 + threadIdx.x;
  out[b] = -0.1f * logf(s[b]);
}

extern "C" void kernel_launch(void* const* d_in, const int* in_sizes, int n_in,
                              void* d_out, int out_size, void* d_ws, size_t ws_size,
                              hipStream_t stream) {
  const float* g1 = (const float*)d_in[0];
  const float* W  = (const float*)d_in[1];
  float* out = (float*)d_out;

  char* ws = (char*)d_ws;
  float* s       = (float*)ws;                          // 32768 * 4 = 128 KiB
  float* sq      = (float*)(ws + 131072);               // 4096 * 4  = 16 KiB
  ushort_t* nWt  = (ushort_t*)(ws + 147456);            // 4096*1024*2 = 8 MiB
  ushort_t* g1b  = (ushort_t*)(ws + 147456 + 8388608);  // 32768*1024*2 = 64 MiB

  hipMemsetAsync(ws, 0, 147456, stream);  // zero s + sq

  colnorm_partial<<<dim3(16, 16), 256, 0, stream>>>(W, sq);
  convert_b<<<dim3(64, 16), 256, 0, stream>>>(W, sq, nWt);
  convert_a<<<dim3(16384), 256, 0, stream>>>(g1, g1b);
  gemm_expsum<<<dim3(32, 256), 256, 0, stream>>>(g1b, nWt, s);
  finish_kernel<<<dim3(128), 256, 0, stream>>>(s, out);
}